// Round 18
// baseline (240.479 us; speedup 1.0000x reference)
//
#include <hip/hip_runtime.h>
#include <hip/hip_bf16.h>

typedef unsigned short u16;
typedef unsigned int u32;
typedef __attribute__((ext_vector_type(8))) short bf16x8;
typedef __attribute__((ext_vector_type(4))) float f32x4;
typedef __attribute__((ext_vector_type(2))) unsigned u32x2v;

constexpr int Bn = 4;
constexpr int Sn = 2048;
constexpr int En = 1024;
constexpr int Hn = 16;
constexpr int Dn = 64;
constexpr int Kd = 1024;

__device__ __forceinline__ u16 f2b(float f) {
  union { float f; unsigned u; } v; v.f = f;
  unsigned u = v.u;
  return (u16)((u + 0x7fffu + ((u >> 16) & 1u)) >> 16);  // RNE
}

__device__ __forceinline__ u32 cvtpk_bf16(float lo, float hi) {
  u32 r;
  asm("v_cvt_pk_bf16_f32 %0, %1, %2" : "=v"(r) : "v"(lo), "v"(hi));
  return r;
}

__device__ __forceinline__ void gl_lds16(const u16* g, u16* l) {
  __builtin_amdgcn_global_load_lds(
      (const __attribute__((address_space(1))) void*)g,
      (__attribute__((address_space(3))) void*)l, 16, 0, 0);
}

// permlane chain: rows r0..r3 are 16-lane groups.
__device__ __forceinline__ void plchain(u32& a, u32& b) {
  u32x2v s = __builtin_amdgcn_permlane32_swap(a, b, false, false);
  u32x2v t = __builtin_amdgcn_permlane16_swap(s[0], s[1], false, false);
  a = t[0]; b = t[1];
}

// cross-row (lane±16/±32) sum reduce on VALU pipe via self-swap
__device__ __forceinline__ float redsum_cross(float r) {
  union { float f; u32 u; } v; v.f = r;
  u32x2v s = __builtin_amdgcn_permlane32_swap(v.u, v.u, false, false);
  union { u32 u; float f; } x, y;
  x.u = s[0]; y.u = s[1];
  float m = x.f + y.f;
  union { float f; u32 u; } w; w.f = m;
  u32x2v t = __builtin_amdgcn_permlane16_swap(w.u, w.u, false, false);
  x.u = t[0]; y.u = t[1];
  return x.f + y.f;
}

// ---------------- elementwise fp32 -> bf16 ----------------
__global__ __launch_bounds__(256) void conv_act(const float* __restrict__ in,
                                                u16* __restrict__ out, int n8) {
  int i = blockIdx.x * blockDim.x + threadIdx.x;
  const int stride = gridDim.x * blockDim.x;
  for (; i < n8; i += stride) {
    const float4* p = (const float4*)(in + (size_t)i * 8);
    float4 a = p[0], b = p[1];
    union { u32 w[4]; bf16x8 v; } r;
    r.w[0] = cvtpk_bf16(a.x, a.y); r.w[1] = cvtpk_bf16(a.z, a.w);
    r.w[2] = cvtpk_bf16(b.x, b.y); r.w[3] = cvtpk_bf16(b.z, b.w);
    *(bf16x8*)(out + (size_t)i * 8) = r.v;
  }
}

// ---------------- weight transpose+convert x3: W fp32 [K][N] -> Wt bf16 [N][K] ----
__global__ __launch_bounds__(256) void conv_wt3(
    const float* __restrict__ W0, const float* __restrict__ W1,
    const float* __restrict__ W2, u16* __restrict__ T0,
    u16* __restrict__ T1, u16* __restrict__ T2) {
  const float* W = (blockIdx.z == 0) ? W0 : (blockIdx.z == 1) ? W1 : W2;
  u16* Wt = (blockIdx.z == 0) ? T0 : (blockIdx.z == 1) ? T1 : T2;
  __shared__ float ts[64][65];
  const int t = threadIdx.x;
  const int k0 = blockIdx.y * 64, n0 = blockIdx.x * 64;
  const int r = t >> 4, c4 = (t & 15) * 4;
  #pragma unroll
  for (int i = 0; i < 4; i++) {
    float4 v = *(const float4*)&W[(size_t)(k0 + i * 16 + r) * En + n0 + c4];
    ts[i * 16 + r][c4 + 0] = v.x;
    ts[i * 16 + r][c4 + 1] = v.y;
    ts[i * 16 + r][c4 + 2] = v.z;
    ts[i * 16 + r][c4 + 3] = v.w;
  }
  __syncthreads();
  const int n = t >> 2, kc = (t & 3) * 16;
  u32 w8[8];
  #pragma unroll
  for (int j = 0; j < 8; j++)
    w8[j] = cvtpk_bf16(ts[kc + 2 * j][n], ts[kc + 2 * j + 1][n]);
  *(bf16x8*)&Wt[(size_t)(n0 + n) * Kd + k0 + kc]     = *(bf16x8*)&w8[0];
  *(bf16x8*)&Wt[(size_t)(n0 + n) * Kd + k0 + kc + 8] = *(bf16x8*)&w8[4];
}

// single-weight variant (Wo after attention)
__global__ __launch_bounds__(256) void conv_wt(const float* __restrict__ W,
                                               u16* __restrict__ Wt) {
  __shared__ float ts[64][65];
  const int t = threadIdx.x;
  const int k0 = blockIdx.y * 64, n0 = blockIdx.x * 64;
  const int r = t >> 4, c4 = (t & 15) * 4;
  #pragma unroll
  for (int i = 0; i < 4; i++) {
    float4 v = *(const float4*)&W[(size_t)(k0 + i * 16 + r) * En + n0 + c4];
    ts[i * 16 + r][c4 + 0] = v.x;
    ts[i * 16 + r][c4 + 1] = v.y;
    ts[i * 16 + r][c4 + 2] = v.z;
    ts[i * 16 + r][c4 + 3] = v.w;
  }
  __syncthreads();
  const int n = t >> 2, kc = (t & 3) * 16;
  u32 w8[8];
  #pragma unroll
  for (int j = 0; j < 8; j++)
    w8[j] = cvtpk_bf16(ts[kc + 2 * j][n], ts[kc + 2 * j + 1][n]);
  *(bf16x8*)&Wt[(size_t)(n0 + n) * Kd + k0 + kc]     = *(bf16x8*)&w8[0];
  *(bf16x8*)&Wt[(size_t)(n0 + n) * Kd + k0 + kc + 8] = *(bf16x8*)&w8[4];
}

// ---------------- GEMM (BM=128, BN=64, BK=64; grid 1024, 4 blocks/CU) --------
// Mechanism: double block-level TLP (independent barriers) so one block's
// vmcnt(0)+barrier drain hides under another's compute. 4 waves x (32 rows
// x 64 cols) each; acc[2][4]; LDS 24KB/block; VGPR ~110 (< 128 cliff).
// Bijective XCD swizzle: XCD x -> brow panels [8x,8x+8) x all 16 bcols
// (A panels 2MB + B 2MB = 4MB = one L2, same as before).
template<int OUT_MODE>
__global__ __launch_bounds__(256) void gemm_k(
    const u16* __restrict__ A, const u16* __restrict__ Bt,
    const float* __restrict__ biasp, void* __restrict__ Cp, float alpha)
{
  constexpr int BK = 64;
  __shared__ u16 As[128 * BK];
  __shared__ u16 Bs[64 * BK];
  const int tid = threadIdx.x;
  const int lane = tid & 63, wave = tid >> 6;
  const int sid = (blockIdx.x & 7) * 128 + (blockIdx.x >> 3);   // 1024 blocks
  const int brow = (sid >> 4) * 128, bcol = (sid & 15) * 64;
  const int wrow = wave * 32;
  const int fr = lane & 15, fk = (lane >> 4) * 8, rq = (lane >> 4) * 4;

  const int lr = lane >> 3, lc = (lane & 7) * 8;
  const u16* Ag = A  + (size_t)(brow + 32 * wave + lr) * Kd + lc;
  const u16* Bg = Bt + (size_t)(bcol + 16 * wave + lr) * Kd + lc;
  u16* Asw = &As[(32 * wave) * BK];
  u16* Bsw = &Bs[(16 * wave) * BK];

  f32x4 acc[2][4] = {};

  for (int kt = 0; kt < Kd; kt += BK) {
    __syncthreads();
    #pragma unroll
    for (int i = 0; i < 4; i++)
      gl_lds16(Ag + kt + (size_t)(8 * i) * Kd, Asw + (8 * i) * BK);
    #pragma unroll
    for (int i = 0; i < 2; i++)
      gl_lds16(Bg + kt + (size_t)(8 * i) * Kd, Bsw + (8 * i) * BK);
    __syncthreads();
    bf16x8 af[2][2], bfv[4][2];
    #pragma unroll
    for (int m = 0; m < 2; m++)
      #pragma unroll
      for (int ks = 0; ks < 2; ks++)
        af[m][ks] = *(const bf16x8*)&As[(wrow + m * 16 + fr) * BK + ks * 32 + fk];
    #pragma unroll
    for (int n = 0; n < 4; n++)
      #pragma unroll
      for (int ks = 0; ks < 2; ks++)
        bfv[n][ks] = *(const bf16x8*)&Bs[(n * 16 + fr) * BK + ks * 32 + fk];
    #pragma unroll
    for (int ks = 0; ks < 2; ks++)
      #pragma unroll
      for (int m = 0; m < 2; m++)
        #pragma unroll
        for (int n = 0; n < 4; n++)
          acc[m][n] = __builtin_amdgcn_mfma_f32_16x16x32_bf16(af[m][ks], bfv[n][ks], acc[m][n], 0, 0, 0);
  }

  #pragma unroll
  for (int m = 0; m < 2; m++) {
    #pragma unroll
    for (int n = 0; n < 4; n++) {
      const int row0 = brow + wrow + m * 16 + rq;
      const int col  = bcol + n * 16 + fr;
      const float bi = biasp[col];
      if constexpr (OUT_MODE == 0) {
        #pragma unroll
        for (int j = 0; j < 4; j++)
          ((float*)Cp)[(size_t)(row0 + j) * En + col] = (acc[m][n][j] + bi) * alpha;
      } else if constexpr (OUT_MODE == 1) {
        #pragma unroll
        for (int j = 0; j < 4; j++)
          ((u16*)Cp)[(size_t)(row0 + j) * En + col] = f2b((acc[m][n][j] + bi) * alpha);
      } else {
        u16 t4[4];
        #pragma unroll
        for (int j = 0; j < 4; j++) t4[j] = f2b((acc[m][n][j] + bi) * alpha);
        int bb = row0 >> 11, s = row0 & (Sn - 1);
        int hh = col >> 6, d = col & (Dn - 1);
        uint2 pk;
        pk.x = (u32)t4[0] | ((u32)t4[1] << 16);
        pk.y = (u32)t4[2] | ((u32)t4[3] << 16);
        *(uint2*)&((u16*)Cp)[((size_t)(bb * Hn + hh) * Dn + d) * Sn + s] = pk;
      }
    }
  }
}

// ---------------- Flash attention (QB=256: 4 waves x 64 q-rows) --------------
// R11-exact (best measured: 103 us). m==0 softmax, permlane redistribution,
// 2-buf gl_lds staging, bijective XCD swizzle (8 bh/XCD). Parked optimum.
#define SWZ(row, unit) (((row) * 64) + ((((unit) ^ ((row) & 7))) * 8))

__global__ __launch_bounds__(256) void attn_k(
    const u16* __restrict__ Qw, const u16* __restrict__ Kw,
    const u16* __restrict__ Vt, u16* __restrict__ Cw)
{
  constexpr int KB = 64, NT = Sn / KB, TSZ = 64 * 64;
  __shared__ u16 Ks[2 * TSZ];
  __shared__ u16 Vs[2 * TSZ];
  const int tid = threadIdx.x, lane = tid & 63, wave = tid >> 6;
  const int id = blockIdx.x;
  const int w = id >> 3;
  const int bh = (id & 7) * 8 + (w >> 3);
  const int qb = w & 7;
  const int b = bh >> 4, h = bh & 15;
  const int qbase = qb * 256 + wave * 64;
  const int fr = lane & 15, fk = (lane >> 4) * 8, rq = (lane >> 4) * 4;
  const int g = lane >> 4;

  const u16* Qg  = Qw + (size_t)(b * Sn + qbase) * En + h * Dn;
  const u16* Kg0 = Kw + (size_t)(b * Sn) * En + h * Dn;
  const u16* Vg0 = Vt + (size_t)bh * Dn * Sn;

  bf16x8 qf[4][2];
  #pragma unroll
  for (int qm = 0; qm < 4; qm++)
    #pragma unroll
    for (int ds = 0; ds < 2; ds++)
      qf[qm][ds] = *(const bf16x8*)&Qg[(size_t)(qm * 16 + fr) * En + ds * 32 + fk];

  float li_s[4] = {0.f, 0.f, 0.f, 0.f};
  f32x4 o[4][4] = {};

  const int sr0 = 16 * wave + (lane >> 3);
  const int su  = (lane & 7);

  auto stage = [&](int kv, int bufi) {
    #pragma unroll
    for (int c = 0; c < 2; c++) {
      const int r = sr0 + 8 * c;
      const int u = su ^ (r & 7);
      gl_lds16(Kg0 + (size_t)(kv + r) * En + u * 8, &Ks[bufi * TSZ + (16 * wave + 8 * c) * 64]);
      gl_lds16(Vg0 + (size_t)r * Sn + kv + u * 8,   &Vs[bufi * TSZ + (16 * wave + 8 * c) * 64]);
    }
  };

  stage(0, 0);
  int cur = 0;

  for (int t = 0; t < NT; t++) {
    asm volatile("s_waitcnt vmcnt(0)" ::: "memory");
    __syncthreads();
    if (t + 1 < NT) stage((t + 1) * KB, cur ^ 1);

    // ---- S^T = K @ Q^T  (64k x 64q per wave)
    f32x4 st[4][4] = {};
    const u16* kbase = &Ks[cur * TSZ];
    #pragma unroll
    for (int kb = 0; kb < 4; kb++)
      #pragma unroll
      for (int ds = 0; ds < 2; ds++) {
        bf16x8 kf = *(const bf16x8*)&kbase[SWZ(kb * 16 + fr, ds * 4 + g)];
        #pragma unroll
        for (int qm = 0; qm < 4; qm++)
          st[kb][qm] = __builtin_amdgcn_mfma_f32_16x16x32_bf16(kf, qf[qm][ds], st[kb][qm], 0, 0, 0);
      }

    // ---- softmax numerator (m==0) + PV A-fragments
    bf16x8 pa[4][2];
    #pragma unroll
    for (int qm = 0; qm < 4; qm++) {
      float p[4][4];
      #pragma unroll
      for (int kb = 0; kb < 4; kb++)
        #pragma unroll
        for (int j = 0; j < 4; j++)
          p[kb][j] = __builtin_amdgcn_exp2f(st[kb][qm][j]);
      float s0 = (p[0][0] + p[0][1]) + (p[0][2] + p[0][3]);
      float s1 = (p[1][0] + p[1][1]) + (p[1][2] + p[1][3]);
      float s2 = (p[2][0] + p[2][1]) + (p[2][2] + p[2][3]);
      float s3 = (p[3][0] + p[3][1]) + (p[3][2] + p[3][3]);
      li_s[qm] += redsum_cross((s0 + s1) + (s2 + s3));

      u32 plo[4], phi[4];
      #pragma unroll
      for (int kb = 0; kb < 4; kb++) {
        plo[kb] = cvtpk_bf16(p[kb][0], p[kb][1]);
        phi[kb] = cvtpk_bf16(p[kb][2], p[kb][3]);
      }
      plchain(plo[0], plo[1]);
      plchain(phi[0], phi[1]);
      plchain(plo[2], plo[3]);
      plchain(phi[2], phi[3]);
      union { u32 w[4]; bf16x8 v; } A0, A1;
      A0.w[0] = plo[0]; A0.w[1] = phi[0]; A0.w[2] = plo[1]; A0.w[3] = phi[1];
      A1.w[0] = plo[2]; A1.w[1] = phi[2]; A1.w[2] = plo[3]; A1.w[3] = phi[3];
      pa[qm][0] = A0.v;
      pa[qm][1] = A1.v;
    }

    // ---- O += P @ V  (V fragments read once, reused by 4 qm)
    {
      const u16* vbase = &Vs[cur * TSZ];
      #pragma unroll
      for (int nd = 0; nd < 4; nd++)
        #pragma unroll
        for (int ks = 0; ks < 2; ks++) {
          bf16x8 vf = *(const bf16x8*)&vbase[SWZ(nd * 16 + fr, ks * 4 + g)];
          #pragma unroll
          for (int qm = 0; qm < 4; qm++)
            o[qm][nd] = __builtin_amdgcn_mfma_f32_16x16x32_bf16(pa[qm][ks], vf, o[qm][nd], 0, 0, 0);
        }
    }
    cur ^= 1;
  }

  // ---- epilogue: O /= l
  #pragma unroll
  for (int qm = 0; qm < 4; qm++) {
    float inv = 1.0f / li_s[qm];
    float rinv[4];
    #pragma unroll
    for (int j = 0; j < 4; j++) rinv[j] = __shfl(inv, (lane & 0x30) | (rq + j));
    #pragma unroll
    for (int nd = 0; nd < 4; nd++)
      #pragma unroll
      for (int j = 0; j < 4; j++) {
        int s = qbase + qm * 16 + rq + j;
        int d = nd * 16 + fr;
        Cw[((size_t)(b * Sn + s)) * En + h * Dn + d] = f2b(o[qm][nd][j] * rinv[j]);
      }
  }
}

extern "C" void kernel_launch(void* const* d_in, const int* in_sizes, int n_in,
                              void* d_out, int out_size, void* d_ws, size_t ws_size,
                              hipStream_t stream) {
  const float* q  = (const float*)d_in[0];
  const float* k  = (const float*)d_in[1];
  const float* v  = (const float*)d_in[2];
  const float* Wq = (const float*)d_in[3];
  const float* Wk = (const float*)d_in[4];
  const float* Wv = (const float*)d_in[5];
  const float* Wo = (const float*)d_in[6];
  const float* bq = (const float*)d_in[7];
  const float* bk = (const float*)d_in[8];
  const float* bv = (const float*)d_in[9];
  const float* bo = (const float*)d_in[10];

  const size_t NE = (size_t)Bn * Sn * En;
  const size_t WE = (size_t)En * En;
  u16* Qbf = (u16*)d_ws;
  u16* Kbf = Qbf + NE;
  u16* Vtw = Kbf + NE;
  u16* Cws = Vtw + NE;
  u16* Xact = (u16*)d_out;
  u16* WtQ  = Xact + NE;
  u16* WtK  = WtQ + WE;
  u16* WtV  = WtK + WE;
  u16* WtO  = Qbf;                // Wo^T reuses Q buffer after attention

  dim3 blk(256);
  dim3 gwt3(16, 16, 3);
  const int n8 = (int)(NE / 8);
  const float aq = 0.125f * 1.44269504088896340736f;

  conv_wt3<<<gwt3, blk, 0, stream>>>(Wq, Wk, Wv, WtQ, WtK, WtV);

  conv_act<<<2048, blk, 0, stream>>>(q, Xact, n8);
  gemm_k<1><<<1024, blk, 0, stream>>>(Xact, WtQ, bq, Qbf, aq);

  conv_act<<<2048, blk, 0, stream>>>(k, Xact, n8);
  gemm_k<1><<<1024, blk, 0, stream>>>(Xact, WtK, bk, Kbf, 1.0f);

  conv_act<<<2048, blk, 0, stream>>>(v, Xact, n8);
  gemm_k<2><<<1024, blk, 0, stream>>>(Xact, WtV, bv, Vtw, 1.0f);

  attn_k<<<dim3(8 * Bn * Hn), blk, 0, stream>>>(Qbf, Kbf, Vtw, Cws);

  conv_wt<<<dim3(16, 16), blk, 0, stream>>>(Wo, WtO);
  gemm_k<0><<<1024, blk, 0, stream>>>(Cws, WtO, bo, d_out, 1.0f);
}

// Round 19
// 237.295 us; speedup vs baseline: 1.0134x; 1.0134x over previous
//
#include <hip/hip_runtime.h>
#include <hip/hip_bf16.h>

typedef unsigned short u16;
typedef unsigned int u32;
typedef __attribute__((ext_vector_type(8))) short bf16x8;
typedef __attribute__((ext_vector_type(4))) float f32x4;
typedef __attribute__((ext_vector_type(2))) unsigned u32x2v;

constexpr int Bn = 4;
constexpr int Sn = 2048;
constexpr int En = 1024;
constexpr int Hn = 16;
constexpr int Dn = 64;
constexpr int Kd = 1024;

__device__ __forceinline__ u16 f2b(float f) {
  union { float f; unsigned u; } v; v.f = f;
  unsigned u = v.u;
  return (u16)((u + 0x7fffu + ((u >> 16) & 1u)) >> 16);  // RNE
}

__device__ __forceinline__ u32 cvtpk_bf16(float lo, float hi) {
  u32 r;
  asm("v_cvt_pk_bf16_f32 %0, %1, %2" : "=v"(r) : "v"(lo), "v"(hi));
  return r;
}

__device__ __forceinline__ void gl_lds16(const u16* g, u16* l) {
  __builtin_amdgcn_global_load_lds(
      (const __attribute__((address_space(1))) void*)g,
      (__attribute__((address_space(3))) void*)l, 16, 0, 0);
}

// permlane chain: rows r0..r3 are 16-lane groups.
__device__ __forceinline__ void plchain(u32& a, u32& b) {
  u32x2v s = __builtin_amdgcn_permlane32_swap(a, b, false, false);
  u32x2v t = __builtin_amdgcn_permlane16_swap(s[0], s[1], false, false);
  a = t[0]; b = t[1];
}

// cross-row (lane±16/±32) sum reduce on VALU pipe via self-swap
__device__ __forceinline__ float redsum_cross(float r) {
  union { float f; u32 u; } v; v.f = r;
  u32x2v s = __builtin_amdgcn_permlane32_swap(v.u, v.u, false, false);
  union { u32 u; float f; } x, y;
  x.u = s[0]; y.u = s[1];
  float m = x.f + y.f;
  union { float f; u32 u; } w; w.f = m;
  u32x2v t = __builtin_amdgcn_permlane16_swap(w.u, w.u, false, false);
  x.u = t[0]; y.u = t[1];
  return x.f + y.f;
}

// ---------------- elementwise fp32 -> bf16 ----------------
__global__ __launch_bounds__(256) void conv_act(const float* __restrict__ in,
                                                u16* __restrict__ out, int n8) {
  int i = blockIdx.x * blockDim.x + threadIdx.x;
  const int stride = gridDim.x * blockDim.x;
  for (; i < n8; i += stride) {
    const float4* p = (const float4*)(in + (size_t)i * 8);
    float4 a = p[0], b = p[1];
    union { u32 w[4]; bf16x8 v; } r;
    r.w[0] = cvtpk_bf16(a.x, a.y); r.w[1] = cvtpk_bf16(a.z, a.w);
    r.w[2] = cvtpk_bf16(b.x, b.y); r.w[3] = cvtpk_bf16(b.z, b.w);
    *(bf16x8*)(out + (size_t)i * 8) = r.v;
  }
}

// ---------------- weight transpose+convert x3: W fp32 [K][N] -> Wt bf16 [N][K] ----
__global__ __launch_bounds__(256) void conv_wt3(
    const float* __restrict__ W0, const float* __restrict__ W1,
    const float* __restrict__ W2, u16* __restrict__ T0,
    u16* __restrict__ T1, u16* __restrict__ T2) {
  const float* W = (blockIdx.z == 0) ? W0 : (blockIdx.z == 1) ? W1 : W2;
  u16* Wt = (blockIdx.z == 0) ? T0 : (blockIdx.z == 1) ? T1 : T2;
  __shared__ float ts[64][65];
  const int t = threadIdx.x;
  const int k0 = blockIdx.y * 64, n0 = blockIdx.x * 64;
  const int r = t >> 4, c4 = (t & 15) * 4;
  #pragma unroll
  for (int i = 0; i < 4; i++) {
    float4 v = *(const float4*)&W[(size_t)(k0 + i * 16 + r) * En + n0 + c4];
    ts[i * 16 + r][c4 + 0] = v.x;
    ts[i * 16 + r][c4 + 1] = v.y;
    ts[i * 16 + r][c4 + 2] = v.z;
    ts[i * 16 + r][c4 + 3] = v.w;
  }
  __syncthreads();
  const int n = t >> 2, kc = (t & 3) * 16;
  u32 w8[8];
  #pragma unroll
  for (int j = 0; j < 8; j++)
    w8[j] = cvtpk_bf16(ts[kc + 2 * j][n], ts[kc + 2 * j + 1][n]);
  *(bf16x8*)&Wt[(size_t)(n0 + n) * Kd + k0 + kc]     = *(bf16x8*)&w8[0];
  *(bf16x8*)&Wt[(size_t)(n0 + n) * Kd + k0 + kc + 8] = *(bf16x8*)&w8[4];
}

// single-weight variant (Wo after attention)
__global__ __launch_bounds__(256) void conv_wt(const float* __restrict__ W,
                                               u16* __restrict__ Wt) {
  __shared__ float ts[64][65];
  const int t = threadIdx.x;
  const int k0 = blockIdx.y * 64, n0 = blockIdx.x * 64;
  const int r = t >> 4, c4 = (t & 15) * 4;
  #pragma unroll
  for (int i = 0; i < 4; i++) {
    float4 v = *(const float4*)&W[(size_t)(k0 + i * 16 + r) * En + n0 + c4];
    ts[i * 16 + r][c4 + 0] = v.x;
    ts[i * 16 + r][c4 + 1] = v.y;
    ts[i * 16 + r][c4 + 2] = v.z;
    ts[i * 16 + r][c4 + 3] = v.w;
  }
  __syncthreads();
  const int n = t >> 2, kc = (t & 3) * 16;
  u32 w8[8];
  #pragma unroll
  for (int j = 0; j < 8; j++)
    w8[j] = cvtpk_bf16(ts[kc + 2 * j][n], ts[kc + 2 * j + 1][n]);
  *(bf16x8*)&Wt[(size_t)(n0 + n) * Kd + k0 + kc]     = *(bf16x8*)&w8[0];
  *(bf16x8*)&Wt[(size_t)(n0 + n) * Kd + k0 + kc + 8] = *(bf16x8*)&w8[4];
}

// ---------------- GEMM (m97 structure + XCD swizzle): C = (A @ Bt^T + b)*alpha --
template<int OUT_MODE>
__global__ __launch_bounds__(256) void gemm_k(
    const u16* __restrict__ A, const u16* __restrict__ Bt,
    const float* __restrict__ biasp, void* __restrict__ Cp, float alpha)
{
  constexpr int BK = 64;
  __shared__ u16 As[128 * BK];
  __shared__ u16 Bs[128 * BK];
  const int tid = threadIdx.x;
  const int lane = tid & 63, wave = tid >> 6;
  const int sid = (blockIdx.x & 7) * 64 + (blockIdx.x >> 3);
  const int brow = (sid >> 3) * 128, bcol = (sid & 7) * 128;
  const int wrow = (wave >> 1) * 64, wcol = (wave & 1) * 64;
  const int fr = lane & 15, fk = (lane >> 4) * 8, rq = (lane >> 4) * 4;

  const int lr = lane >> 3, lc = (lane & 7) * 8;
  const u16* Ag = A  + (size_t)(brow + 32 * wave + lr) * Kd + lc;
  const u16* Bg = Bt + (size_t)(bcol + 32 * wave + lr) * Kd + lc;
  u16* Asw = &As[(32 * wave) * BK];
  u16* Bsw = &Bs[(32 * wave) * BK];

  f32x4 acc[4][4] = {};

  for (int kt = 0; kt < Kd; kt += BK) {
    __syncthreads();
    #pragma unroll
    for (int i = 0; i < 4; i++) {
      gl_lds16(Ag + kt + (size_t)(8 * i) * Kd, Asw + (8 * i) * BK);
      gl_lds16(Bg + kt + (size_t)(8 * i) * Kd, Bsw + (8 * i) * BK);
    }
    __syncthreads();
    bf16x8 af[4][2], bfv[4][2];
    #pragma unroll
    for (int m = 0; m < 4; m++)
      #pragma unroll
      for (int ks = 0; ks < 2; ks++)
        af[m][ks] = *(const bf16x8*)&As[(wrow + m * 16 + fr) * BK + ks * 32 + fk];
    #pragma unroll
    for (int n = 0; n < 4; n++)
      #pragma unroll
      for (int ks = 0; ks < 2; ks++)
        bfv[n][ks] = *(const bf16x8*)&Bs[(wcol + n * 16 + fr) * BK + ks * 32 + fk];
    #pragma unroll
    for (int ks = 0; ks < 2; ks++)
      #pragma unroll
      for (int m = 0; m < 4; m++)
        #pragma unroll
        for (int n = 0; n < 4; n++)
          acc[m][n] = __builtin_amdgcn_mfma_f32_16x16x32_bf16(af[m][ks], bfv[n][ks], acc[m][n], 0, 0, 0);
  }

  #pragma unroll
  for (int m = 0; m < 4; m++) {
    #pragma unroll
    for (int n = 0; n < 4; n++) {
      const int row0 = brow + wrow + m * 16 + rq;
      const int col  = bcol + wcol + n * 16 + fr;
      const float bi = biasp[col];
      if constexpr (OUT_MODE == 0) {
        #pragma unroll
        for (int j = 0; j < 4; j++)
          ((float*)Cp)[(size_t)(row0 + j) * En + col] = (acc[m][n][j] + bi) * alpha;
      } else if constexpr (OUT_MODE == 1) {
        #pragma unroll
        for (int j = 0; j < 4; j++)
          ((u16*)Cp)[(size_t)(row0 + j) * En + col] = f2b((acc[m][n][j] + bi) * alpha);
      } else {
        u16 t4[4];
        #pragma unroll
        for (int j = 0; j < 4; j++) t4[j] = f2b((acc[m][n][j] + bi) * alpha);
        int bb = row0 >> 11, s = row0 & (Sn - 1);
        int hh = col >> 6, d = col & (Dn - 1);
        uint2 pk;
        pk.x = (u32)t4[0] | ((u32)t4[1] << 16);
        pk.y = (u32)t4[2] | ((u32)t4[3] << 16);
        *(uint2*)&((u16*)Cp)[((size_t)(bb * Hn + hh) * Dn + d) * Sn + s] = pk;
      }
    }
  }
}

// ---------------- Flash attention (QB=256: 4 waves x 64 q-rows) --------------
// R11-exact (best measured: 103 us). m==0 softmax, permlane redistribution,
// 2-buf gl_lds staging, bijective XCD swizzle (8 bh/XCD). Parked optimum.
#define SWZ(row, unit) (((row) * 64) + ((((unit) ^ ((row) & 7))) * 8))

__global__ __launch_bounds__(256) void attn_k(
    const u16* __restrict__ Qw, const u16* __restrict__ Kw,
    const u16* __restrict__ Vt, u16* __restrict__ Cw)
{
  constexpr int KB = 64, NT = Sn / KB, TSZ = 64 * 64;
  __shared__ u16 Ks[2 * TSZ];
  __shared__ u16 Vs[2 * TSZ];
  const int tid = threadIdx.x, lane = tid & 63, wave = tid >> 6;
  const int id = blockIdx.x;
  const int w = id >> 3;
  const int bh = (id & 7) * 8 + (w >> 3);
  const int qb = w & 7;
  const int b = bh >> 4, h = bh & 15;
  const int qbase = qb * 256 + wave * 64;
  const int fr = lane & 15, fk = (lane >> 4) * 8, rq = (lane >> 4) * 4;
  const int g = lane >> 4;

  const u16* Qg  = Qw + (size_t)(b * Sn + qbase) * En + h * Dn;
  const u16* Kg0 = Kw + (size_t)(b * Sn) * En + h * Dn;
  const u16* Vg0 = Vt + (size_t)bh * Dn * Sn;

  bf16x8 qf[4][2];
  #pragma unroll
  for (int qm = 0; qm < 4; qm++)
    #pragma unroll
    for (int ds = 0; ds < 2; ds++)
      qf[qm][ds] = *(const bf16x8*)&Qg[(size_t)(qm * 16 + fr) * En + ds * 32 + fk];

  float li_s[4] = {0.f, 0.f, 0.f, 0.f};
  f32x4 o[4][4] = {};

  const int sr0 = 16 * wave + (lane >> 3);
  const int su  = (lane & 7);

  auto stage = [&](int kv, int bufi) {
    #pragma unroll
    for (int c = 0; c < 2; c++) {
      const int r = sr0 + 8 * c;
      const int u = su ^ (r & 7);
      gl_lds16(Kg0 + (size_t)(kv + r) * En + u * 8, &Ks[bufi * TSZ + (16 * wave + 8 * c) * 64]);
      gl_lds16(Vg0 + (size_t)r * Sn + kv + u * 8,   &Vs[bufi * TSZ + (16 * wave + 8 * c) * 64]);
    }
  };

  stage(0, 0);
  int cur = 0;

  for (int t = 0; t < NT; t++) {
    asm volatile("s_waitcnt vmcnt(0)" ::: "memory");
    __syncthreads();
    if (t + 1 < NT) stage((t + 1) * KB, cur ^ 1);

    // ---- S^T = K @ Q^T  (64k x 64q per wave)
    f32x4 st[4][4] = {};
    const u16* kbase = &Ks[cur * TSZ];
    #pragma unroll
    for (int kb = 0; kb < 4; kb++)
      #pragma unroll
      for (int ds = 0; ds < 2; ds++) {
        bf16x8 kf = *(const bf16x8*)&kbase[SWZ(kb * 16 + fr, ds * 4 + g)];
        #pragma unroll
        for (int qm = 0; qm < 4; qm++)
          st[kb][qm] = __builtin_amdgcn_mfma_f32_16x16x32_bf16(kf, qf[qm][ds], st[kb][qm], 0, 0, 0);
      }

    // ---- softmax numerator (m==0) + PV A-fragments
    bf16x8 pa[4][2];
    #pragma unroll
    for (int qm = 0; qm < 4; qm++) {
      float p[4][4];
      #pragma unroll
      for (int kb = 0; kb < 4; kb++)
        #pragma unroll
        for (int j = 0; j < 4; j++)
          p[kb][j] = __builtin_amdgcn_exp2f(st[kb][qm][j]);
      // tree sum (short dep chains)
      float s0 = (p[0][0] + p[0][1]) + (p[0][2] + p[0][3]);
      float s1 = (p[1][0] + p[1][1]) + (p[1][2] + p[1][3]);
      float s2 = (p[2][0] + p[2][1]) + (p[2][2] + p[2][3]);
      float s3 = (p[3][0] + p[3][1]) + (p[3][2] + p[3][3]);
      li_s[qm] += redsum_cross((s0 + s1) + (s2 + s3));

      u32 plo[4], phi[4];
      #pragma unroll
      for (int kb = 0; kb < 4; kb++) {
        plo[kb] = cvtpk_bf16(p[kb][0], p[kb][1]);
        phi[kb] = cvtpk_bf16(p[kb][2], p[kb][3]);
      }
      plchain(plo[0], plo[1]);
      plchain(phi[0], phi[1]);
      plchain(plo[2], plo[3]);
      plchain(phi[2], phi[3]);
      union { u32 w[4]; bf16x8 v; } A0, A1;
      A0.w[0] = plo[0]; A0.w[1] = phi[0]; A0.w[2] = plo[1]; A0.w[3] = phi[1];
      A1.w[0] = plo[2]; A1.w[1] = phi[2]; A1.w[2] = plo[3]; A1.w[3] = phi[3];
      pa[qm][0] = A0.v;
      pa[qm][1] = A1.v;
    }

    // ---- O += P @ V  (V fragments read once, reused by 4 qm)
    {
      const u16* vbase = &Vs[cur * TSZ];
      #pragma unroll
      for (int nd = 0; nd < 4; nd++)
        #pragma unroll
        for (int ks = 0; ks < 2; ks++) {
          bf16x8 vf = *(const bf16x8*)&vbase[SWZ(nd * 16 + fr, ks * 4 + g)];
          #pragma unroll
          for (int qm = 0; qm < 4; qm++)
            o[qm][nd] = __builtin_amdgcn_mfma_f32_16x16x32_bf16(pa[qm][ks], vf, o[qm][nd], 0, 0, 0);
        }
    }
    cur ^= 1;
  }

  // ---- epilogue: O /= l
  #pragma unroll
  for (int qm = 0; qm < 4; qm++) {
    float inv = 1.0f / li_s[qm];
    float rinv[4];
    #pragma unroll
    for (int j = 0; j < 4; j++) rinv[j] = __shfl(inv, (lane & 0x30) | (rq + j));
    #pragma unroll
    for (int nd = 0; nd < 4; nd++)
      #pragma unroll
      for (int j = 0; j < 4; j++) {
        int s = qbase + qm * 16 + rq + j;
        int d = nd * 16 + fr;
        Cw[((size_t)(b * Sn + s)) * En + h * Dn + d] = f2b(o[qm][nd][j] * rinv[j]);
      }
  }
}

extern "C" void kernel_launch(void* const* d_in, const int* in_sizes, int n_in,
                              void* d_out, int out_size, void* d_ws, size_t ws_size,
                              hipStream_t stream) {
  const float* q  = (const float*)d_in[0];
  const float* k  = (const float*)d_in[1];
  const float* v  = (const float*)d_in[2];
  const float* Wq = (const float*)d_in[3];
  const float* Wk = (const float*)d_in[4];
  const float* Wv = (const float*)d_in[5];
  const float* Wo = (const float*)d_in[6];
  const float* bq = (const float*)d_in[7];
  const float* bk = (const float*)d_in[8];
  const float* bv = (const float*)d_in[9];
  const float* bo = (const float*)d_in[10];

  const size_t NE = (size_t)Bn * Sn * En;
  const size_t WE = (size_t)En * En;
  u16* Qbf = (u16*)d_ws;
  u16* Kbf = Qbf + NE;
  u16* Vtw = Kbf + NE;
  u16* Cws = Vtw + NE;
  u16* Xact = (u16*)d_out;
  u16* WtQ  = Xact + NE;
  u16* WtK  = WtQ + WE;
  u16* WtV  = WtK + WE;
  u16* WtO  = Qbf;                // Wo^T reuses Q buffer after attention

  dim3 blk(256);
  dim3 gwt3(16, 16, 3);
  const int n8 = (int)(NE / 8);
  const float aq = 0.125f * 1.44269504088896340736f;

  conv_wt3<<<gwt3, blk, 0, stream>>>(Wq, Wk, Wv, WtQ, WtK, WtV);

  conv_act<<<2048, blk, 0, stream>>>(q, Xact, n8);
  gemm_k<1><<<512, blk, 0, stream>>>(Xact, WtQ, bq, Qbf, aq);

  conv_act<<<2048, blk, 0, stream>>>(k, Xact, n8);
  gemm_k<1><<<512, blk, 0, stream>>>(Xact, WtK, bk, Kbf, 1.0f);

  conv_act<<<2048, blk, 0, stream>>>(v, Xact, n8);
  gemm_k<2><<<512, blk, 0, stream>>>(Xact, WtV, bv, Vtw, 1.0f);

  attn_k<<<dim3(8 * Bn * Hn), blk, 0, stream>>>(Qbf, Kbf, Vtw, Cws);

  conv_wt<<<dim3(16, 16), blk, 0, stream>>>(Wo, WtO);
  gemm_k<0><<<512, blk, 0, stream>>>(Cws, WtO, bo, d_out, 1.0f);
}